// Round 3
// baseline (1072.660 us; speedup 1.0000x reference)
//
#include <hip/hip_runtime.h>

#define S_LEN  2048
#define BATCH  1024
#define NL     6
#define CH     16      // timesteps per chunk (x-prefetch granularity)

typedef float f32x2 __attribute__((ext_vector_type(2)));

__device__ __forceinline__ float fexp2(float x) { return __builtin_amdgcn_exp2f(x); }
__device__ __forceinline__ float frcp(float x)  { return __builtin_amdgcn_rcpf(x); }

// quad_perm DPP: xor1=[1,0,3,2]=0xB1, xor2=[2,3,0,1]=0x4E, xor3=[3,2,1,0]=0x1B
template <int CTRL>
__device__ __forceinline__ float dppf(float v) {
    return __int_as_float(__builtin_amdgcn_update_dpp(
        0, __float_as_int(v), CTRL, 0xF, 0xF, true));
}
__device__ __forceinline__ float bpermf(int addr, float v) {
    return __int_as_float(__builtin_amdgcn_ds_bpermute(addr, __float_as_int(v)));
}
// packed fp32 fma: d.lo = a.lo*b.lo + c.lo ; d.hi = a.hi*b.hi + c.hi
__device__ __forceinline__ f32x2 pkfma(f32x2 a, f32x2 b, f32x2 c) {
    f32x2 d;
    asm("v_pk_fma_f32 %0, %1, %2, %3" : "=v"(d) : "v"(a), "v"(b), "v"(c));
    return d;
}

// ONE wave carries the whole 6-layer pipeline for 2 batch elements.
// lane = L*8 + e*4 + j. Lanes 56-63 are feeders publishing x[t] via hsrc.
// Per step: 1 bpermute + 6 DPP + 16 v_pk_fma_f32 (lo=Wh-chain, hi=Wx-chain,
// weights pre-scaled by -log2e / -2log2e so exp2 args come out directly).
// Masking exists only in chunk 0 (pipeline fill); bulk chunks are maskless.
//
// Launch geometry: 1024-thread blocks = 16 waves -> 4 waves PER SIMD. The
// per-wave recurrence leaves ~39% of issue slots idle (bpermute + activation
// chain latency); co-resident waves from other batch pairs fill them (TLP).
__global__ __launch_bounds__(1024, 1) void lstm_wavepipe(
    const float* __restrict__ x, const float* __restrict__ w_ih,
    const float* __restrict__ w_hh, const float* __restrict__ b_ih,
    const float* __restrict__ b_hh, const float* __restrict__ reg_w,
    const float* __restrict__ reg_b, float* __restrict__ out) {
    const int tid  = threadIdx.x;
    const int wv   = tid >> 6;                   // wave id within block, 0..15
    const int lane = tid & 63;
    const int L    = lane >> 3;
    const int e    = (lane >> 2) & 1;
    const int j    = lane & 3;
    const int b    = (blockIdx.x * 16 + wv) * 2 + e;
    const int Lc   = (L < NL) ? L : NL - 1;      // clamp for safe weight loads
    const bool isFeeder = (lane >= 56);
    const bool isOut    = (L == 5) && (j == 0);

    const float KGc = -2.885390082f;             // -2*log2(e)
    const float KIc = -1.442695041f;             // -log2(e)

    // ---- weight preload: packed {Wh, Wx}, pre-scaled; term m = unit j^m ----
    f32x2 WP[4][4], GbP[4];
#pragma unroll
    for (int g = 0; g < 4; ++g) {
        const float kk = (g == 2) ? KGc : KIc;
        const int row = Lc * 16 + g * 4 + j;     // PyTorch gate order i,f,g,o
#pragma unroll
        for (int m = 0; m < 4; ++m) {
            f32x2 w;
            w.x = w_hh[row * 4 + (j ^ m)] * kk;  // lo lane: recurrent chain
            w.y = w_ih[row * 4 + (j ^ m)] * kk;  // hi lane: input chain
            WP[g][m] = w;
        }
        f32x2 gb; gb.x = (b_ih[row] + b_hh[row]) * kk; gb.y = 0.0f;
        GbP[g] = gb;
    }
    const float regw = reg_w[j];
    const float regb = reg_b[0];
    const int bpaddr = ((lane >= 8) ? (lane - 8) : (lane + 56)) << 2;

    float h = 0.0f, c = 0.0f;
    float bufA[CH], bufB[CH], su[CH];
    uint32_t wi = (uint32_t)(b * 4 + j);         // running word offset into x
#pragma unroll
    for (int u = 0; u < CH; ++u) { bufA[u] = x[wi]; wi += 4096; }   // t=0..15

// PREFM_: 0=no prefetch, 1=stream next 16 t's, 2=clamped (replicate t=2047)
#define RUN_CHUNK(cc_, cur_, nxt_, MASKF_, PREFM_, GUARDF_, NSTEPS_) do {      \
    if ((PREFM_) == 1) {                                                       \
        _Pragma("unroll")                                                      \
        for (int u = 0; u < CH; ++u) { nxt_[u] = x[wi]; wi += 4096; }          \
    } else if ((PREFM_) == 2) {                                                \
        const float xl = x[2047u * 4096u + (uint32_t)(b * 4 + j)];             \
        _Pragma("unroll")                                                      \
        for (int u = 0; u < CH; ++u) nxt_[u] = xl;                             \
    }                                                                          \
    _Pragma("unroll")                                                          \
    for (int u = 0; u < (NSTEPS_); ++u) {                                      \
        const float hsrc = isFeeder ? cur_[u] : h;   /* feeders publish x */   \
        const float hup  = bpermf(bpaddr, hsrc);     /* h from layer above */  \
        const float hv1 = dppf<0xB1>(h),   hv2 = dppf<0x4E>(h),                \
                    hv3 = dppf<0x1B>(h);                                       \
        const float xv1 = dppf<0xB1>(hup), xv2 = dppf<0x4E>(hup),              \
                    xv3 = dppf<0x1B>(hup);                                     \
        f32x2 V0, V1, V2, V3;                                                  \
        V0.x = h;   V0.y = hup;                                                \
        V1.x = hv1; V1.y = xv1;                                                \
        V2.x = hv2; V2.y = xv2;                                                \
        V3.x = hv3; V3.y = xv3;                                                \
        f32x2 Ai = pkfma(WP[0][0], V0, GbP[0]);                                \
        f32x2 Af = pkfma(WP[1][0], V0, GbP[1]);                                \
        f32x2 Ag = pkfma(WP[2][0], V0, GbP[2]);                                \
        f32x2 Ao = pkfma(WP[3][0], V0, GbP[3]);                                \
        Ai = pkfma(WP[0][1], V1, Ai); Af = pkfma(WP[1][1], V1, Af);            \
        Ag = pkfma(WP[2][1], V1, Ag); Ao = pkfma(WP[3][1], V1, Ao);            \
        Ai = pkfma(WP[0][2], V2, Ai); Af = pkfma(WP[1][2], V2, Af);            \
        Ag = pkfma(WP[2][2], V2, Ag); Ao = pkfma(WP[3][2], V2, Ao);            \
        Ai = pkfma(WP[0][3], V3, Ai); Af = pkfma(WP[1][3], V3, Af);            \
        Ag = pkfma(WP[2][3], V3, Ag); Ao = pkfma(WP[3][3], V3, Ao);            \
        const float si = frcp(1.0f + fexp2(Ai.x + Ai.y));                      \
        const float sf = frcp(1.0f + fexp2(Af.x + Af.y));                      \
        const float tg = fmaf(2.0f, frcp(1.0f + fexp2(Ag.x + Ag.y)), -1.0f);   \
        const float so = frcp(1.0f + fexp2(Ao.x + Ao.y));                      \
        const float cn = fmaf(sf, c, si * tg);                                 \
        const float th = fmaf(2.0f, frcp(1.0f + fexp2(cn * KGc)), -1.0f);      \
        const float hn = so * th;                                              \
        if (MASKF_) {                                                          \
            const bool act = (u >= L);               /* pipeline-fill gate */  \
            c = act ? cn : c;                                                  \
            h = act ? hn : h;                                                  \
        } else { c = cn; h = hn; }                                             \
        float s = h * regw;                          /* linear head */         \
        s += dppf<0xB1>(s);                                                    \
        s += dppf<0x4E>(s);                                                    \
        su[u] = s + regb;                                                      \
    }                                                                          \
    if (isOut) {                                                               \
        const int base = (cc_) * CH - (NL - 1);                                \
        _Pragma("unroll")                                                      \
        for (int u = 0; u < (NSTEPS_); ++u) {                                  \
            const int t = base + u;                                            \
            if (!(GUARDF_) || ((t >= 0) && (t < S_LEN)))                       \
                out[(size_t)t * BATCH + b] = su[u];                            \
        }                                                                      \
    }                                                                          \
} while (0)

    // chunk 0: masked (pipeline fill), prefetch t=16..31 into bufB
    RUN_CHUNK(0, bufA, bufB, 1, 1, 1, CH);
    // bulk: chunks 1..126, maskless, guardless, ping-pong buffers
#pragma unroll 1
    for (int cc = 1; cc < 127; cc += 2) {
        RUN_CHUNK(cc,     bufB, bufA, 0, 1, 0, CH);
        RUN_CHUNK(cc + 1, bufA, bufB, 0, 1, 0, CH);
    }
    // chunk 127: last real x tile; clamped prefetch (t=2047 replicated)
    RUN_CHUNK(127, bufB, bufA, 0, 2, 0, CH);
    // chunk 128: 5 drain steps produce t=2043..2047 on L5
    RUN_CHUNK(128, bufA, bufB, 0, 0, 0, 5);
#undef RUN_CHUNK
}

extern "C" void kernel_launch(void* const* d_in, const int* in_sizes, int n_in,
                              void* d_out, int out_size, void* d_ws, size_t ws_size,
                              hipStream_t stream) {
    const float* x     = (const float*)d_in[0];
    const float* w_ih  = (const float*)d_in[1];
    const float* w_hh  = (const float*)d_in[2];
    const float* b_ih  = (const float*)d_in[3];
    const float* b_hh  = (const float*)d_in[4];
    const float* reg_w = (const float*)d_in[5];
    const float* reg_b = (const float*)d_in[6];
    float* out = (float*)d_out;

    // 32 blocks x 16 waves: 512 waves total, 4 waves per SIMD on 32 CUs.
    dim3 grid(BATCH / 32);
    dim3 block(1024);
    hipLaunchKernelGGL(lstm_wavepipe, grid, block, 0, stream, x, w_ih, w_hh,
                       b_ih, b_hh, reg_w, reg_b, out);
}

// Round 4
// 649.659 us; speedup vs baseline: 1.6511x; 1.6511x over previous
//
#include <hip/hip_runtime.h>

#define S_LEN  2048
#define BATCH  1024
#define NL     6
#define CH     8       // timesteps per chunk (x-prefetch granularity)

typedef float f32x2 __attribute__((ext_vector_type(2)));

__device__ __forceinline__ float fexp2(float x) { return __builtin_amdgcn_exp2f(x); }
__device__ __forceinline__ float frcp(float x)  { return __builtin_amdgcn_rcpf(x); }

// quad_perm DPP: xor1=[1,0,3,2]=0xB1, xor2=[2,3,0,1]=0x4E, xor3=[3,2,1,0]=0x1B
template <int CTRL>
__device__ __forceinline__ float dppf(float v) {
    return __int_as_float(__builtin_amdgcn_update_dpp(
        0, __float_as_int(v), CTRL, 0xF, 0xF, true));
}
__device__ __forceinline__ float bpermf(int addr, float v) {
    return __int_as_float(__builtin_amdgcn_ds_bpermute(addr, __float_as_int(v)));
}
// packed fp32 fma: d.lo = a.lo*b.lo + c.lo ; d.hi = a.hi*b.hi + c.hi
__device__ __forceinline__ f32x2 pkfma(f32x2 a, f32x2 b, f32x2 c) {
    f32x2 d;
    asm("v_pk_fma_f32 %0, %1, %2, %3" : "=v"(d) : "v"(a), "v"(b), "v"(c));
    return d;
}

// ONE wave carries the 6-layer pipeline for TWO independent batch pairs
// (4 batch elements), software-interleaved in the same instruction stream.
// A single pipeline leaves ~40% of the SIMD issue slots idle on dependency
// stalls (bpermute + exp2/rcp chains); the second pair's independent
// instructions fill them. Weights are lane-indexed and shared across pairs.
// lane = L*8 + e*4 + j; lanes 56-63 feed x[t]; no LDS, no syncthreads.
__global__ __launch_bounds__(64, 1) void lstm_wavepipe(
    const float* __restrict__ x, const float* __restrict__ w_ih,
    const float* __restrict__ w_hh, const float* __restrict__ b_ih,
    const float* __restrict__ b_hh, const float* __restrict__ reg_w,
    const float* __restrict__ reg_b, float* __restrict__ out) {
    const int lane = threadIdx.x;
    const int L    = lane >> 3;
    const int e    = (lane >> 2) & 1;
    const int j    = lane & 3;
    const int b0   = blockIdx.x * 4 + e;         // pair A batch element
    const int b1   = b0 + 2;                     // pair B batch element
    const int Lc   = (L < NL) ? L : NL - 1;      // clamp for safe weight loads
    const bool isFeeder = (lane >= 56);
    const bool isOut    = (L == 5) && (j == 0);

    const float KGc = -2.885390082f;             // -2*log2(e)
    const float KIc = -1.442695041f;             // -log2(e)

    // ---- weight preload: packed {Wh, Wx}, pre-scaled; term m = unit j^m ----
    f32x2 WP[4][4], GbP[4];
#pragma unroll
    for (int g = 0; g < 4; ++g) {
        const float kk = (g == 2) ? KGc : KIc;
        const int row = Lc * 16 + g * 4 + j;     // PyTorch gate order i,f,g,o
#pragma unroll
        for (int m = 0; m < 4; ++m) {
            f32x2 w;
            w.x = w_hh[row * 4 + (j ^ m)] * kk;  // lo lane: recurrent chain
            w.y = w_ih[row * 4 + (j ^ m)] * kk;  // hi lane: input chain
            WP[g][m] = w;
        }
        f32x2 gb; gb.x = (b_ih[row] + b_hh[row]) * kk; gb.y = 0.0f;
        GbP[g] = gb;
    }
    const float regw = reg_w[j];
    const float regb = reg_b[0];
    const int bpaddr = ((lane >= 8) ? (lane - 8) : (lane + 56)) << 2;

    float h0 = 0.0f, c0 = 0.0f, h1 = 0.0f, c1 = 0.0f;
    float bufP0[CH], bufQ0[CH], su0[CH];
    float bufP1[CH], bufQ1[CH], su1[CH];
    uint32_t wi0 = (uint32_t)(b0 * 4 + j);       // running word offsets into x
    uint32_t wi1 = (uint32_t)(b1 * 4 + j);
#pragma unroll
    for (int u = 0; u < CH; ++u) { bufP0[u] = x[wi0]; wi0 += 4096; }
#pragma unroll
    for (int u = 0; u < CH; ++u) { bufP1[u] = x[wi1]; wi1 += 4096; }

// one interleaved pipeline step for both pairs
#define STEP2(u_, cur0_, cur1_, MASKF_) do {                                   \
    const float hsA = isFeeder ? cur0_[u_] : h0;                               \
    const float hsB = isFeeder ? cur1_[u_] : h1;                               \
    const float huA = bpermf(bpaddr, hsA);                                     \
    const float huB = bpermf(bpaddr, hsB);                                     \
    const float hA1 = dppf<0xB1>(h0),  hB1 = dppf<0xB1>(h1);                   \
    const float hA2 = dppf<0x4E>(h0),  hB2 = dppf<0x4E>(h1);                   \
    const float hA3 = dppf<0x1B>(h0),  hB3 = dppf<0x1B>(h1);                   \
    const float xA1 = dppf<0xB1>(huA), xB1 = dppf<0xB1>(huB);                  \
    const float xA2 = dppf<0x4E>(huA), xB2 = dppf<0x4E>(huB);                  \
    const float xA3 = dppf<0x1B>(huA), xB3 = dppf<0x1B>(huB);                  \
    f32x2 VA0, VA1, VA2, VA3, VB0, VB1, VB2, VB3;                              \
    VA0.x = h0;  VA0.y = huA;  VB0.x = h1;  VB0.y = huB;                       \
    VA1.x = hA1; VA1.y = xA1;  VB1.x = hB1; VB1.y = xB1;                       \
    VA2.x = hA2; VA2.y = xA2;  VB2.x = hB2; VB2.y = xB2;                       \
    VA3.x = hA3; VA3.y = xA3;  VB3.x = hB3; VB3.y = xB3;                       \
    f32x2 AiA = pkfma(WP[0][0], VA0, GbP[0]);                                  \
    f32x2 AiB = pkfma(WP[0][0], VB0, GbP[0]);                                  \
    f32x2 AfA = pkfma(WP[1][0], VA0, GbP[1]);                                  \
    f32x2 AfB = pkfma(WP[1][0], VB0, GbP[1]);                                  \
    f32x2 AgA = pkfma(WP[2][0], VA0, GbP[2]);                                  \
    f32x2 AgB = pkfma(WP[2][0], VB0, GbP[2]);                                  \
    f32x2 AoA = pkfma(WP[3][0], VA0, GbP[3]);                                  \
    f32x2 AoB = pkfma(WP[3][0], VB0, GbP[3]);                                  \
    AiA = pkfma(WP[0][1], VA1, AiA); AiB = pkfma(WP[0][1], VB1, AiB);          \
    AfA = pkfma(WP[1][1], VA1, AfA); AfB = pkfma(WP[1][1], VB1, AfB);          \
    AgA = pkfma(WP[2][1], VA1, AgA); AgB = pkfma(WP[2][1], VB1, AgB);          \
    AoA = pkfma(WP[3][1], VA1, AoA); AoB = pkfma(WP[3][1], VB1, AoB);          \
    AiA = pkfma(WP[0][2], VA2, AiA); AiB = pkfma(WP[0][2], VB2, AiB);          \
    AfA = pkfma(WP[1][2], VA2, AfA); AfB = pkfma(WP[1][2], VB2, AfB);          \
    AgA = pkfma(WP[2][2], VA2, AgA); AgB = pkfma(WP[2][2], VB2, AgB);          \
    AoA = pkfma(WP[3][2], VA2, AoA); AoB = pkfma(WP[3][2], VB2, AoB);          \
    AiA = pkfma(WP[0][3], VA3, AiA); AiB = pkfma(WP[0][3], VB3, AiB);          \
    AfA = pkfma(WP[1][3], VA3, AfA); AfB = pkfma(WP[1][3], VB3, AfB);          \
    AgA = pkfma(WP[2][3], VA3, AgA); AgB = pkfma(WP[2][3], VB3, AgB);          \
    AoA = pkfma(WP[3][3], VA3, AoA); AoB = pkfma(WP[3][3], VB3, AoB);          \
    const float eiA = fexp2(AiA.x + AiA.y), eiB = fexp2(AiB.x + AiB.y);        \
    const float efA = fexp2(AfA.x + AfA.y), efB = fexp2(AfB.x + AfB.y);        \
    const float egA = fexp2(AgA.x + AgA.y), egB = fexp2(AgB.x + AgB.y);        \
    const float eoA = fexp2(AoA.x + AoA.y), eoB = fexp2(AoB.x + AoB.y);        \
    /* paired reciprocals: 1/p = q*rcp(p*q), 1/q = p*rcp(p*q) */               \
    const float piA = 1.0f + eiA, pfA = 1.0f + efA;                            \
    const float piB = 1.0f + eiB, pfB = 1.0f + efB;                            \
    const float rifA = frcp(piA * pfA), rifB = frcp(piB * pfB);                \
    const float siA = pfA * rifA, sfA = piA * rifA;                            \
    const float siB = pfB * rifB, sfB = piB * rifB;                            \
    const float pgA = 1.0f + egA, poA = 1.0f + eoA;                            \
    const float pgB = 1.0f + egB, poB = 1.0f + eoB;                            \
    const float rgoA = frcp(pgA * poA), rgoB = frcp(pgB * poB);                \
    const float tgA = fmaf(2.0f, poA * rgoA, -1.0f), soA = pgA * rgoA;         \
    const float tgB = fmaf(2.0f, poB * rgoB, -1.0f), soB = pgB * rgoB;         \
    const float cnA = fmaf(sfA, c0, siA * tgA);                                \
    const float cnB = fmaf(sfB, c1, siB * tgB);                                \
    const float thA = fmaf(2.0f, frcp(1.0f + fexp2(cnA * KGc)), -1.0f);        \
    const float thB = fmaf(2.0f, frcp(1.0f + fexp2(cnB * KGc)), -1.0f);        \
    const float hnA = soA * thA, hnB = soB * thB;                              \
    if (MASKF_) {                                                              \
        const bool act = (u_ >= L);                  /* pipeline-fill gate */  \
        c0 = act ? cnA : c0;  h0 = act ? hnA : h0;                             \
        c1 = act ? cnB : c1;  h1 = act ? hnB : h1;                             \
    } else { c0 = cnA; h0 = hnA; c1 = cnB; h1 = hnB; }                         \
    float sA = h0 * regw, sB = h1 * regw;            /* linear head */         \
    sA += dppf<0xB1>(sA);  sB += dppf<0xB1>(sB);                               \
    sA += dppf<0x4E>(sA);  sB += dppf<0x4E>(sB);                               \
    su0[u_] = sA + regb;   su1[u_] = sB + regb;                                \
} while (0)

// PREFM_: 0=no prefetch, 1=stream next CH t's, 2=clamped (replicate t=2047)
#define RUN_CHUNK2(cc_, cur0_, nxt0_, cur1_, nxt1_, MASKF_, PREFM_, GUARDF_, NSTEPS_) do { \
    if ((PREFM_) == 1) {                                                       \
        _Pragma("unroll")                                                      \
        for (int u = 0; u < CH; ++u) { nxt0_[u] = x[wi0]; wi0 += 4096; }       \
        _Pragma("unroll")                                                      \
        for (int u = 0; u < CH; ++u) { nxt1_[u] = x[wi1]; wi1 += 4096; }       \
    } else if ((PREFM_) == 2) {                                                \
        const float xl0 = x[2047u * 4096u + (uint32_t)(b0 * 4 + j)];           \
        const float xl1 = x[2047u * 4096u + (uint32_t)(b1 * 4 + j)];           \
        _Pragma("unroll")                                                      \
        for (int u = 0; u < CH; ++u) { nxt0_[u] = xl0; nxt1_[u] = xl1; }       \
    }                                                                          \
    _Pragma("unroll")                                                          \
    for (int u = 0; u < (NSTEPS_); ++u) STEP2(u, cur0_, cur1_, MASKF_);        \
    if (isOut) {                                                               \
        const int base = (cc_) * CH - (NL - 1);                                \
        _Pragma("unroll")                                                      \
        for (int u = 0; u < (NSTEPS_); ++u) {                                  \
            const int t = base + u;                                            \
            if (!(GUARDF_) || ((t >= 0) && (t < S_LEN))) {                     \
                out[(size_t)t * BATCH + b0] = su0[u];                          \
                out[(size_t)t * BATCH + b1] = su1[u];                          \
            }                                                                  \
        }                                                                      \
    }                                                                          \
} while (0)

    // chunk 0: masked (pipeline fill), prefetch t=8..15 into Q
    RUN_CHUNK2(0, bufP0, bufQ0, bufP1, bufQ1, 1, 1, 1, CH);
    // bulk: chunks 1..254, maskless, guardless, ping-pong buffers
#pragma unroll 1
    for (int cc = 1; cc < 255; cc += 2) {
        RUN_CHUNK2(cc,     bufQ0, bufP0, bufQ1, bufP1, 0, 1, 0, CH);
        RUN_CHUNK2(cc + 1, bufP0, bufQ0, bufP1, bufQ1, 0, 1, 0, CH);
    }
    // chunk 255: last real x tile (t=2040..2047); clamped prefetch
    RUN_CHUNK2(255, bufQ0, bufP0, bufQ1, bufP1, 0, 2, 0, CH);
    // chunk 256: 5 drain steps produce t=2043..2047 on L5
    RUN_CHUNK2(256, bufP0, bufQ0, bufP1, bufQ1, 0, 0, 0, 5);
#undef RUN_CHUNK2
#undef STEP2
}

extern "C" void kernel_launch(void* const* d_in, const int* in_sizes, int n_in,
                              void* d_out, int out_size, void* d_ws, size_t ws_size,
                              hipStream_t stream) {
    const float* x     = (const float*)d_in[0];
    const float* w_ih  = (const float*)d_in[1];
    const float* w_hh  = (const float*)d_in[2];
    const float* b_ih  = (const float*)d_in[3];
    const float* b_hh  = (const float*)d_in[4];
    const float* reg_w = (const float*)d_in[5];
    const float* reg_b = (const float*)d_in[6];
    float* out = (float*)d_out;

    // 256 single-wave blocks, each carrying 2 interleaved batch pairs.
    dim3 grid(BATCH / 4);
    dim3 block(64);
    hipLaunchKernelGGL(lstm_wavepipe, grid, block, 0, stream, x, w_ih, w_hh,
                       b_ih, b_hh, reg_w, reg_b, out);
}

// Round 5
// 408.216 us; speedup vs baseline: 2.6277x; 1.5915x over previous
//
#include <hip/hip_runtime.h>

#define S_LEN  2048
#define BATCH  1024
#define NL     6
#define CH     16      // timesteps per chunk (x-prefetch granularity)

typedef float f32x2 __attribute__((ext_vector_type(2)));

__device__ __forceinline__ float fexp2(float x) { return __builtin_amdgcn_exp2f(x); }
__device__ __forceinline__ float frcp(float x)  { return __builtin_amdgcn_rcpf(x); }

// quad_perm DPP: xor1=[1,0,3,2]=0xB1, xor2=[2,3,0,1]=0x4E, xor3=[3,2,1,0]=0x1B
template <int CTRL>
__device__ __forceinline__ float dppf(float v) {
    return __int_as_float(__builtin_amdgcn_update_dpp(
        0, __float_as_int(v), CTRL, 0xF, 0xF, true));
}
__device__ __forceinline__ float bpermf(int addr, float v) {
    return __int_as_float(__builtin_amdgcn_ds_bpermute(addr, __float_as_int(v)));
}
// packed fp32 fma: d.lo = a.lo*b.lo + c.lo ; d.hi = a.hi*b.hi + c.hi
__device__ __forceinline__ f32x2 pkfma(f32x2 a, f32x2 b, f32x2 c) {
    f32x2 d;
    asm("v_pk_fma_f32 %0, %1, %2, %3" : "=v"(d) : "v"(a), "v"(b), "v"(c));
    return d;
}

// ONE wave carries the whole 6-layer pipeline for 2 batch elements.
// lane = L*8 + e*4 + j. Lanes 56-63 feed x[t]; lanes 48-55 (L==6) carry the
// LINEAR HEAD: they already receive L5's h via the existing bpermute, and
// their gate-i pkfma chain is loaded with reg_w/reg_b so the head dot-product
// costs zero extra instructions (su = Ai.x+Ai.y on those lanes).
// The handoff bpermute for step n+1 is issued at the END of step n (same h
// value) so its LDS latency hides under the loop tail + next step's DPPs.
__global__ __launch_bounds__(64, 1) void lstm_wavepipe(
    const float* __restrict__ x, const float* __restrict__ w_ih,
    const float* __restrict__ w_hh, const float* __restrict__ b_ih,
    const float* __restrict__ b_hh, const float* __restrict__ reg_w,
    const float* __restrict__ reg_b, float* __restrict__ out) {
    const int lane = threadIdx.x;
    const int L    = lane >> 3;
    const int e    = (lane >> 2) & 1;
    const int j    = lane & 3;
    const int b    = blockIdx.x * 2 + e;
    const bool isFeeder = (lane >= 56);
    const bool isOut    = (L == 6) && (j == 0);  // lanes 48 (e=0), 52 (e=1)

    const float KGc = -2.885390082f;             // -2*log2(e)
    const float KIc = -1.442695041f;             // -log2(e)

    // ---- weight preload: packed {Wh, Wx}, pre-scaled; term m = unit j^m ----
    f32x2 WP[4][4], GbP[4];
    if (L < NL) {
#pragma unroll
        for (int g = 0; g < 4; ++g) {
            const float kk = (g == 2) ? KGc : KIc;
            const int row = L * 16 + g * 4 + j;  // PyTorch gate order i,f,g,o
#pragma unroll
            for (int m = 0; m < 4; ++m) {
                f32x2 w;
                w.x = w_hh[row * 4 + (j ^ m)] * kk;  // lo: recurrent chain
                w.y = w_ih[row * 4 + (j ^ m)] * kk;  // hi: input chain
                WP[g][m] = w;
            }
            f32x2 gb; gb.x = (b_ih[row] + b_hh[row]) * kk; gb.y = 0.0f;
            GbP[g] = gb;
        }
    } else {
        // head lanes (and feeders, harmlessly): gate-i hi-chain = linear head
#pragma unroll
        for (int g = 0; g < 4; ++g) {
#pragma unroll
            for (int m = 0; m < 4; ++m) {
                f32x2 w; w.x = 0.0f;
                w.y = (g == 0) ? reg_w[j ^ m] : 0.0f;
                WP[g][m] = w;
            }
            f32x2 gb; gb.x = 0.0f; gb.y = (g == 0) ? reg_b[0] : 0.0f;
            GbP[g] = gb;
        }
    }
    const int bpaddr = ((lane >= 8) ? (lane - 8) : (lane + 56)) << 2;

    float h = 0.0f, c = 0.0f;
    float bufP[CH], bufQ[CH], su[CH];
    uint32_t wi = (uint32_t)(b * 4 + j);         // running word offset into x
#pragma unroll
    for (int u = 0; u < CH; ++u) { bufP[u] = x[wi]; wi += 4096; }   // t=0..15

    // prologue handoff: feeders publish x[0], everyone else publishes h=0
    float hup = bpermf(bpaddr, isFeeder ? bufP[0] : 0.0f);

// one pipeline step; NXV_ = x value the feeders publish for the NEXT step
#define STEP(u_, NXV_, MASKF_) do {                                            \
    const float hv1 = dppf<0xB1>(h),   hv2 = dppf<0x4E>(h),                    \
                hv3 = dppf<0x1B>(h);                                           \
    const float xv1 = dppf<0xB1>(hup), xv2 = dppf<0x4E>(hup),                  \
                xv3 = dppf<0x1B>(hup);                                         \
    f32x2 V0, V1, V2, V3;                                                      \
    V0.x = h;   V0.y = hup;                                                    \
    V1.x = hv1; V1.y = xv1;                                                    \
    V2.x = hv2; V2.y = xv2;                                                    \
    V3.x = hv3; V3.y = xv3;                                                    \
    f32x2 Ai = pkfma(WP[0][0], V0, GbP[0]);                                    \
    f32x2 Af = pkfma(WP[1][0], V0, GbP[1]);                                    \
    f32x2 Ag = pkfma(WP[2][0], V0, GbP[2]);                                    \
    f32x2 Ao = pkfma(WP[3][0], V0, GbP[3]);                                    \
    Ai = pkfma(WP[0][1], V1, Ai); Af = pkfma(WP[1][1], V1, Af);                \
    Ag = pkfma(WP[2][1], V1, Ag); Ao = pkfma(WP[3][1], V1, Ao);                \
    Ai = pkfma(WP[0][2], V2, Ai); Af = pkfma(WP[1][2], V2, Af);                \
    Ag = pkfma(WP[2][2], V2, Ag); Ao = pkfma(WP[3][2], V2, Ao);                \
    Ai = pkfma(WP[0][3], V3, Ai); Af = pkfma(WP[1][3], V3, Af);                \
    Ag = pkfma(WP[2][3], V3, Ag); Ao = pkfma(WP[3][3], V3, Ao);                \
    const float pI = Ai.x + Ai.y;                /* head value on lanes 48+ */ \
    const float pF = Af.x + Af.y;                                              \
    const float pG = Ag.x + Ag.y;                                              \
    const float pO = Ao.x + Ao.y;                                              \
    const float si = frcp(1.0f + fexp2(pI));                                   \
    const float sf = frcp(1.0f + fexp2(pF));                                   \
    const float tg = fmaf(2.0f, frcp(1.0f + fexp2(pG)), -1.0f);                \
    const float so = frcp(1.0f + fexp2(pO));                                   \
    const float cn = fmaf(sf, c, si * tg);                                     \
    const float th = fmaf(2.0f, frcp(1.0f + fexp2(cn * KGc)), -1.0f);          \
    const float hn = so * th;                                                  \
    if (MASKF_) {                                                              \
        const bool act = (u_ >= L);                  /* pipeline-fill gate */  \
        c = act ? cn : c;                                                      \
        h = act ? hn : h;                                                      \
    } else { c = cn; h = hn; }                                                 \
    su[u_] = pI;                                                               \
    const float hsrc = isFeeder ? (NXV_) : h;                                  \
    hup = bpermf(bpaddr, hsrc);                  /* handoff for step n+1 */    \
} while (0)

// PREFM_: 0=no prefetch, 1=stream next 16 t's, 2=clamped (replicate t=2047)
#define RUN_CHUNK(cc_, cur_, nxt_, MASKF_, PREFM_, GUARDF_, NSTEPS_) do {      \
    if ((PREFM_) == 1) {                                                       \
        _Pragma("unroll")                                                      \
        for (int u = 0; u < CH; ++u) { nxt_[u] = x[wi]; wi += 4096; }          \
    } else if ((PREFM_) == 2) {                                                \
        const float xl = x[2047u * 4096u + (uint32_t)(b * 4 + j)];             \
        _Pragma("unroll")                                                      \
        for (int u = 0; u < CH; ++u) nxt_[u] = xl;                             \
    }                                                                          \
    _Pragma("unroll")                                                          \
    for (int u = 0; u < (NSTEPS_); ++u) {                                      \
        if (u < CH - 1) STEP(u, cur_[u + 1], MASKF_);                          \
        else            STEP(u, nxt_[0],     MASKF_);                          \
    }                                                                          \
    if (isOut) {                                                               \
        const int base = (cc_) * CH - 6;            /* head lags L5 by one */  \
        _Pragma("unroll")                                                      \
        for (int u = 0; u < (NSTEPS_); ++u) {                                  \
            const int t = base + u;                                            \
            if (!(GUARDF_) || ((t >= 0) && (t < S_LEN)))                       \
                out[(size_t)t * BATCH + b] = su[u];                            \
        }                                                                      \
    }                                                                          \
} while (0)

    // chunk 0: masked (pipeline fill), prefetch t=16..31 into bufQ
    RUN_CHUNK(0, bufP, bufQ, 1, 1, 1, CH);
    // bulk: chunks 1..126, maskless, guardless, ping-pong buffers
#pragma unroll 1
    for (int cc = 1; cc < 127; cc += 2) {
        RUN_CHUNK(cc,     bufQ, bufP, 0, 1, 0, CH);
        RUN_CHUNK(cc + 1, bufP, bufQ, 0, 1, 0, CH);
    }
    // chunk 127: last real x tile; clamped prefetch (t=2047 replicated)
    RUN_CHUNK(127, bufQ, bufP, 0, 2, 0, CH);
    // chunk 128: 6 drain steps emit head values for t=2042..2047
    RUN_CHUNK(128, bufP, bufQ, 0, 0, 0, 6);
#undef RUN_CHUNK
#undef STEP
}

extern "C" void kernel_launch(void* const* d_in, const int* in_sizes, int n_in,
                              void* d_out, int out_size, void* d_ws, size_t ws_size,
                              hipStream_t stream) {
    const float* x     = (const float*)d_in[0];
    const float* w_ih  = (const float*)d_in[1];
    const float* w_hh  = (const float*)d_in[2];
    const float* b_ih  = (const float*)d_in[3];
    const float* b_hh  = (const float*)d_in[4];
    const float* reg_w = (const float*)d_in[5];
    const float* reg_b = (const float*)d_in[6];
    float* out = (float*)d_out;

    dim3 grid(BATCH / 2);   // 512 single-wave blocks, 2 batch elements each
    dim3 block(64);
    hipLaunchKernelGGL(lstm_wavepipe, grid, block, 0, stream, x, w_ih, w_hh,
                       b_ih, b_hh, reg_w, reg_b, out);
}

// Round 6
// 340.606 us; speedup vs baseline: 3.1493x; 1.1985x over previous
//
#include <hip/hip_runtime.h>

#define S_LEN  2048
#define BATCH  1024
#define NL     6
#define CH     16      // timesteps per chunk (x-prefetch granularity)

typedef float f32x2 __attribute__((ext_vector_type(2)));

__device__ __forceinline__ float fexp2(float x) { return __builtin_amdgcn_exp2f(x); }
__device__ __forceinline__ float frcp(float x)  { return __builtin_amdgcn_rcpf(x); }

// quad_perm DPP: xor1=[1,0,3,2]=0xB1 (partner lane), xor2=[2,3,0,1]=0x4E (u^1)
template <int CTRL>
__device__ __forceinline__ float dppf(float v) {
    return __int_as_float(__builtin_amdgcn_update_dpp(
        0, __float_as_int(v), CTRL, 0xF, 0xF, true));
}
__device__ __forceinline__ float bpermf(int addr, float v) {
    return __int_as_float(__builtin_amdgcn_ds_bpermute(addr, __float_as_int(v)));
}
// lane^4 exchange (u^2) via ds_swizzle BitMode: xor=4, and=0x1F -> 0x101F
__device__ __forceinline__ float swz4(float v) {
    return __int_as_float(__builtin_amdgcn_ds_swizzle(__float_as_int(v), 0x101F));
}
// packed fp32 fma: d.lo = a.lo*b.lo + c.lo ; d.hi = a.hi*b.hi + c.hi
__device__ __forceinline__ f32x2 pkfma(f32x2 a, f32x2 b, f32x2 c) {
    f32x2 d;
    asm("v_pk_fma_f32 %0, %1, %2, %3" : "=v"(d) : "v"(a), "v"(b), "v"(c));
    return d;
}

// ONE wave = ONE batch element; 1024 waves fill all 1024 SIMDs (1 wave/SIMD).
// lane = L*8 + q, q = u*2 + p: L 0..5 layers, L=6 head, L=7 feeders;
// u = unit, p = gate-pair (p=0 -> {i,f}, p=1 -> {g,o}).
// Each lane computes its unit's 2 gate pre-acts in the two pk halves:
//   C1 accumulates {whLo*h[m], wihHi*hup[m]},  C2 {whHi*h[m], wihLo*hup[m]};
//   gateLo = C1.x+C2.y, gateHi = C1.y+C2.x  (biases/scales folded in).
// Operand pairs are NATURAL {h_m, hup_m} pairs: P0={h,hupA}, P1=dpp0x4E(P0),
// P2={swz4(h), bperm^4(h)}, P3=dpp0x4E(P2). Gate gather = 2 quad-perm pulls
// from the partner lane; h-merge = 1 DPP + cndmask. Head value rides in the
// C1.y chain of L=6 lanes (weights = reg_w) -- zero extra instructions.
__global__ __launch_bounds__(64, 1) void lstm_wavepipe(
    const float* __restrict__ x, const float* __restrict__ w_ih,
    const float* __restrict__ w_hh, const float* __restrict__ b_ih,
    const float* __restrict__ b_hh, const float* __restrict__ reg_w,
    const float* __restrict__ reg_b, float* __restrict__ out) {
    const int lane = threadIdx.x;
    const int L    = lane >> 3;
    const int q    = lane & 7;
    const int u    = q >> 1;
    const bool pOdd = (lane & 1);
    const int b    = blockIdx.x;
    const bool isFeeder = (L == 7);
    const bool isOut    = (lane == 48);      // head lane u=0,p=0

    const float KGc = -2.885390082f;         // -2*log2(e)  (tanh gates)
    const float KIc = -1.442695041f;         // -log2(e)    (sigmoid gates)

    // ---- weight preload ----
    f32x2 A1[4], A2[4], PB;
    if (L < NL) {
        const int gLo = pOdd ? 2 : 0;        // i or g
        const int gHi = pOdd ? 3 : 1;        // f or o
        const float klo = pOdd ? KGc : KIc;
        const float khi = KIc;
        const int rowLo = L * 16 + gLo * 4 + u;
        const int rowHi = L * 16 + gHi * 4 + u;
#pragma unroll
        for (int m = 0; m < 4; ++m) {
            const int cm = u ^ m;
            f32x2 a1, a2;
            a1.x = w_hh[rowLo * 4 + cm] * klo;   // lo gate, h terms
            a1.y = w_ih[rowHi * 4 + cm] * khi;   // hi gate, hup terms
            a2.x = w_hh[rowHi * 4 + cm] * khi;   // hi gate, h terms
            a2.y = w_ih[rowLo * 4 + cm] * klo;   // lo gate, hup terms
            A1[m] = a1; A2[m] = a2;
        }
        PB.x = (b_ih[rowLo] + b_hh[rowLo]) * klo;
        PB.y = (b_ih[rowHi] + b_hh[rowHi]) * khi;
    } else if (L == 6) {                     // head: dot(reg_w, hup) in C1.y
#pragma unroll
        for (int m = 0; m < 4; ++m) {
            f32x2 a1; a1.x = 0.0f; a1.y = reg_w[u ^ m];
            A1[m] = a1;
            f32x2 a2; a2.x = 0.0f; a2.y = 0.0f;
            A2[m] = a2;
        }
        PB.x = 0.0f; PB.y = reg_b[0];
    } else {                                 // feeders: all zero
#pragma unroll
        for (int m = 0; m < 4; ++m) {
            f32x2 z; z.x = 0.0f; z.y = 0.0f;
            A1[m] = z; A2[m] = z;
        }
        PB.x = 0.0f; PB.y = 0.0f;
    }
    const float aLo = pOdd ? 2.0f : 1.0f;    // tanh = 2*sig-1, sigmoid = sig
    const float bLo = pOdd ? -1.0f : 0.0f;
    f32x2 Z2; Z2.x = 0.0f; Z2.y = 0.0f;

    const int src   = (lane >= 8) ? (lane - 8) : (lane + 56);
    const int addrA = src << 2;              // layer above, unit u
    const int addrB = (src ^ 4) << 2;        // layer above, unit u^2

    float c = 0.0f;
    float bufP[CH], bufQ[CH], su[CH];
    const uint32_t xcol = (uint32_t)(b * 4 + u);   // all lanes: same 4 words
    uint32_t wi = xcol;
#pragma unroll
    for (int uu = 0; uu < CH; ++uu) { bufP[uu] = x[wi]; wi += 4096; }  // t=0..15

    // prologue: h=0; feeders publish x[0]; issue gathers for step 0
    f32x2 P0, P2;
    {
        const float h0 = isFeeder ? bufP[0] : 0.0f;
        P0.x = h0; P0.y = bpermf(addrA, h0);
        P2.x = swz4(h0); P2.y = bpermf(addrB, h0);
    }

// one pipeline step; NXV_ = x value the feeders publish for the NEXT step
#define STEP(u_, NXV_, MASKF_) do {                                            \
    f32x2 P1, P3;                                                              \
    P1.x = dppf<0x4E>(P0.x); P1.y = dppf<0x4E>(P0.y);                          \
    P3.x = dppf<0x4E>(P2.x); P3.y = dppf<0x4E>(P2.y);                          \
    f32x2 C1 = pkfma(A1[0], P0, PB);                                           \
    f32x2 C2 = pkfma(A2[0], P0, Z2);                                           \
    C1 = pkfma(A1[1], P1, C1); C2 = pkfma(A2[1], P1, C2);                      \
    C1 = pkfma(A1[2], P2, C1); C2 = pkfma(A2[2], P2, C2);                      \
    C1 = pkfma(A1[3], P3, C1); C2 = pkfma(A2[3], P3, C2);                      \
    const float gLo = C1.x + C2.y;                                             \
    const float gHi = C1.y + C2.x;                                             \
    const float rA = frcp(1.0f + fexp2(gLo));                                  \
    const float rB = frcp(1.0f + fexp2(gHi));                                  \
    const float sA = fmaf(aLo, rA, bLo);     /* sig(i) on p=0, tanh(g) p=1 */  \
    const float tg = dppf<0xB1>(sA);         /* p=0 pulls tanh(g) */           \
    const float so = dppf<0xB1>(rB);         /* p=0 pulls sig(o)  */           \
    const float cn = fmaf(rB, c, sA * tg);   /* valid on p=0 lanes */          \
    const float th = fmaf(2.0f, frcp(1.0f + fexp2(cn * KGc)), -1.0f);          \
    const float hn = so * th;                                                  \
    const float hx = dppf<0xB1>(hn);         /* p=1 pulls real h */            \
    float hsel = pOdd ? hx : hn;                                               \
    if (MASKF_) {                                                              \
        const bool act = (u_ >= L);          /* pipeline-fill gate */          \
        c = act ? cn : c;                                                      \
        hsel = act ? hsel : P0.x;                                              \
    } else { c = cn; }                                                         \
    su[u_] = gHi;                            /* head value on L=6 lanes */     \
    const float hpub = isFeeder ? (NXV_) : hsel;                               \
    P0.x = hpub;                                                               \
    P0.y = bpermf(addrA, hpub);              /* hup[u]   for step n+1 */       \
    P2.x = swz4(hpub);                       /* h[u^2]   for step n+1 */       \
    P2.y = bpermf(addrB, hpub);              /* hup[u^2] for step n+1 */       \
} while (0)

// PREFM_: 0=no prefetch, 1=stream next 16 t's, 2=clamped (replicate t=2047)
#define RUN_CHUNK(cc_, cur_, nxt_, MASKF_, PREFM_, GUARDF_, NSTEPS_) do {      \
    if ((PREFM_) == 1) {                                                       \
        _Pragma("unroll")                                                      \
        for (int uu = 0; uu < CH; ++uu) { nxt_[uu] = x[wi]; wi += 4096; }      \
    } else if ((PREFM_) == 2) {                                                \
        const float xl = x[2047u * 4096u + xcol];                              \
        _Pragma("unroll")                                                      \
        for (int uu = 0; uu < CH; ++uu) nxt_[uu] = xl;                         \
    }                                                                          \
    _Pragma("unroll")                                                          \
    for (int uu = 0; uu < (NSTEPS_); ++uu) {                                   \
        if (uu < CH - 1) STEP(uu, cur_[uu + 1], MASKF_);                       \
        else             STEP(uu, nxt_[0],      MASKF_);                       \
    }                                                                          \
    if (isOut) {                                                               \
        const int base = (cc_) * CH - 6;     /* head lags input by 6 steps */  \
        _Pragma("unroll")                                                      \
        for (int uu = 0; uu < (NSTEPS_); ++uu) {                               \
            const int t = base + uu;                                           \
            if (!(GUARDF_) || ((t >= 0) && (t < S_LEN)))                       \
                out[(size_t)t * BATCH + b] = su[uu];                           \
        }                                                                      \
    }                                                                          \
} while (0)

    // chunk 0: masked (pipeline fill), prefetch t=16..31 into bufQ
    RUN_CHUNK(0, bufP, bufQ, 1, 1, 1, CH);
    // bulk: chunks 1..126, maskless, guardless, ping-pong buffers
#pragma unroll 1
    for (int cc = 1; cc < 127; cc += 2) {
        RUN_CHUNK(cc,     bufQ, bufP, 0, 1, 0, CH);
        RUN_CHUNK(cc + 1, bufP, bufQ, 0, 1, 0, CH);
    }
    // chunk 127: last real x tile; clamped prefetch (t=2047 replicated)
    RUN_CHUNK(127, bufQ, bufP, 0, 2, 0, CH);
    // chunk 128: 6 drain steps emit head values for t=2042..2047
    RUN_CHUNK(128, bufP, bufQ, 0, 0, 0, 6);
#undef RUN_CHUNK
#undef STEP
}

extern "C" void kernel_launch(void* const* d_in, const int* in_sizes, int n_in,
                              void* d_out, int out_size, void* d_ws, size_t ws_size,
                              hipStream_t stream) {
    const float* x     = (const float*)d_in[0];
    const float* w_ih  = (const float*)d_in[1];
    const float* w_hh  = (const float*)d_in[2];
    const float* b_ih  = (const float*)d_in[3];
    const float* b_hh  = (const float*)d_in[4];
    const float* reg_w = (const float*)d_in[5];
    const float* reg_b = (const float*)d_in[6];
    float* out = (float*)d_out;

    // 1024 single-wave blocks, one batch element each: 1 wave per SIMD.
    dim3 grid(BATCH);
    dim3 block(64);
    hipLaunchKernelGGL(lstm_wavepipe, grid, block, 0, stream, x, w_ih, w_hh,
                       b_ih, b_hh, reg_w, reg_b, out);
}